// Round 1
// baseline (1747.739 us; speedup 1.0000x reference)
//
#include <hip/hip_runtime.h>
#include <math.h>

#define NN 50000
#define NE 800000
#define NB 64
#define IND 773
#define HIDD 256

__device__ __forceinline__ float lrelu(float x) { return x > 0.f ? x : 0.2f * x; }

// ---------------- fp32 tiled GEMM: C = act(A @ W (+ bias)) ----------------
// 64x64 tile, 256 threads, 4x4 register blocking, BK=16.
template<int RELU, int HASB>
__global__ __launch_bounds__(256) void gemm_f32(const float* __restrict__ A,
                                                const float* __restrict__ W,
                                                const float* __restrict__ bias,
                                                float* __restrict__ C,
                                                int M, int K, int N) {
    __shared__ float As[16][65];  // As[kk][m]
    __shared__ float Bs[16][65];  // Bs[kk][n]
    const int t = threadIdx.x;
    const int tx = t & 15, ty = t >> 4;
    const int bm = blockIdx.x * 64, bn = blockIdx.y * 64;
    float acc[16];
#pragma unroll
    for (int i = 0; i < 16; ++i) acc[i] = 0.f;

    for (int k0 = 0; k0 < K; k0 += 16) {
#pragma unroll
        for (int i = 0; i < 4; ++i) {
            int idx = t + i * 256;
            int m = idx >> 4, kk = idx & 15;
            int gm = bm + m, gk = k0 + kk;
            As[kk][m] = (gm < M && gk < K) ? A[(size_t)gm * K + gk] : 0.f;
        }
#pragma unroll
        for (int i = 0; i < 4; ++i) {
            int idx = t + i * 256;
            int kk = idx >> 6, n = idx & 63;
            int gk = k0 + kk;
            Bs[kk][n] = (gk < K) ? W[(size_t)gk * N + bn + n] : 0.f;
        }
        __syncthreads();
#pragma unroll
        for (int kk = 0; kk < 16; ++kk) {
            float a0 = As[kk][ty * 4 + 0], a1 = As[kk][ty * 4 + 1];
            float a2 = As[kk][ty * 4 + 2], a3 = As[kk][ty * 4 + 3];
            float b0 = Bs[kk][tx * 4 + 0], b1 = Bs[kk][tx * 4 + 1];
            float b2 = Bs[kk][tx * 4 + 2], b3 = Bs[kk][tx * 4 + 3];
            acc[0]  += a0 * b0; acc[1]  += a0 * b1; acc[2]  += a0 * b2; acc[3]  += a0 * b3;
            acc[4]  += a1 * b0; acc[5]  += a1 * b1; acc[6]  += a1 * b2; acc[7]  += a1 * b3;
            acc[8]  += a2 * b0; acc[9]  += a2 * b1; acc[10] += a2 * b2; acc[11] += a2 * b3;
            acc[12] += a3 * b0; acc[13] += a3 * b1; acc[14] += a3 * b2; acc[15] += a3 * b3;
        }
        __syncthreads();
    }
#pragma unroll
    for (int r = 0; r < 4; ++r) {
        int gm = bm + ty * 4 + r;
        if (gm >= M) continue;
#pragma unroll
        for (int c = 0; c < 4; ++c) {
            int gn = bn + tx * 4 + c;
            float v = acc[r * 4 + c];
            if (HASB) v += bias[gn];
            if (RELU) v = fmaxf(v, 0.f);
            C[(size_t)gm * N + gn] = v;
        }
    }
}

// ---------------- attention dot products: a_s/a_d = <hW[n,h,:], att[h,:]> ----------------
template<int HD>
__global__ __launch_bounds__(256) void att_dots(const float* __restrict__ hW,
                                                const float* __restrict__ att_s,
                                                const float* __restrict__ att_d,
                                                float* __restrict__ a_s,
                                                float* __restrict__ a_d) {
    const int CPL = HD / 64;  // channels per lane (4 or 2)
    int node = blockIdx.x * 4 + (threadIdx.x >> 6);
    int lane = threadIdx.x & 63;
    if (node >= NN) return;
    const float* row = hW + (size_t)node * HD + lane * CPL;
    float s = 0.f, d = 0.f;
#pragma unroll
    for (int j = 0; j < CPL; ++j) {
        float v = row[j];
        s += v * att_s[lane * CPL + j];
        d += v * att_d[lane * CPL + j];
    }
    // head group = 16 lanes for both layers; reduce within group
#pragma unroll
    for (int off = 1; off < 16; off <<= 1) {
        s += __shfl_xor(s, off);
        d += __shfl_xor(d, off);
    }
    int h = lane >> 4;
    if ((lane & 15) == 0) {
        a_s[node * 4 + h] = s;
        a_d[node * 4 + h] = d;
    }
}

// ---------------- CSR build ----------------
__global__ void k_hist(const int* __restrict__ ei, int* __restrict__ deg) {
    int e = blockIdx.x * 256 + threadIdx.x;
    if (e >= NE) return;
    atomicAdd(&deg[ei[NE + e]], 1);
}

__global__ __launch_bounds__(1024) void k_scan(const int* __restrict__ deg,
                                               int* __restrict__ row_ptr,
                                               int* __restrict__ cursor) {
    const int CH = (NN + 1023) / 1024;  // 49
    int t = threadIdx.x;
    int lo = t * CH, hi = lo + CH;
    if (hi > NN) hi = NN;
    int s = 0;
    for (int i = lo; i < hi; ++i) s += deg[i];
    __shared__ int sums[1024];
    sums[t] = s;
    __syncthreads();
    for (int off = 1; off < 1024; off <<= 1) {
        int v = (t >= off) ? sums[t - off] : 0;
        __syncthreads();
        sums[t] += v;
        __syncthreads();
    }
    int run = (t == 0) ? 0 : sums[t - 1];
    for (int i = lo; i < hi; ++i) {
        row_ptr[i] = run;
        cursor[i] = run;
        run += deg[i];
    }
    if (t == 1023) row_ptr[NN] = NE;
}

__global__ void k_scatter(const int* __restrict__ ei, int* __restrict__ cursor,
                          int* __restrict__ colidx) {
    int e = blockIdx.x * 256 + threadIdx.x;
    if (e >= NE) return;
    int s = ei[e], d = ei[NE + e];
    int pos = atomicAdd(&cursor[d], 1);
    colidx[pos] = s;
}

// ---------------- fused GAT aggregation (one wave per dst node) ----------------
// out[n,c] = relu( (sum_e alpha_e * hW[src_e,c]) + bias[c] ), online softmax, self-loop implicit.
template<int HD>
__global__ __launch_bounds__(256) void gat_agg(const float* __restrict__ hW,
                                               const float* __restrict__ a_s,
                                               const float* __restrict__ a_d,
                                               const int* __restrict__ row_ptr,
                                               const int* __restrict__ colidx,
                                               const float* __restrict__ bias,
                                               float* __restrict__ out) {
    const int CPL = HD / 64;  // 4 or 2
    int node = blockIdx.x * 4 + (threadIdx.x >> 6);
    int lane = threadIdx.x & 63;
    if (node >= NN) return;
    int h = lane >> 4;  // head = lane/16 for both HD=256 (D=64) and HD=128 (D=32)
    int start = row_ptr[node], end = row_ptr[node + 1];
    float adst = a_d[node * 4 + h];
    float aself = a_s[node * 4 + h];

    // pass 1: max over self-loop + in-edges
    float m = lrelu(aself + adst);
    for (int e = start; e < end; ++e) {
        int s = colidx[e];
        m = fmaxf(m, lrelu(a_s[s * 4 + h] + adst));
    }

    // pass 2: z and weighted accumulation
    float acc[CPL];
    float z;
    {
        float ex = __expf(lrelu(aself + adst) - m);
        z = ex;
        const float* row = hW + (size_t)node * HD + lane * CPL;
        float v[CPL];
        if (CPL == 4) *(float4*)v = *(const float4*)row;
        else          *(float2*)v = *(const float2*)row;
#pragma unroll
        for (int j = 0; j < CPL; ++j) acc[j] = ex * v[j];
    }
    for (int e = start; e < end; ++e) {
        int s = colidx[e];
        float ex = __expf(lrelu(a_s[s * 4 + h] + adst) - m);
        z += ex;
        const float* row = hW + (size_t)s * HD + lane * CPL;
        float v[CPL];
        if (CPL == 4) *(float4*)v = *(const float4*)row;
        else          *(float2*)v = *(const float2*)row;
#pragma unroll
        for (int j = 0; j < CPL; ++j) acc[j] += ex * v[j];
    }
    float inv = 1.f / (z + 1e-16f);
    float* orow = out + (size_t)node * HD + lane * CPL;
#pragma unroll
    for (int j = 0; j < CPL; ++j)
        orow[j] = fmaxf(acc[j] * inv + bias[lane * CPL + j], 0.f);
}

// ---------------- pooling + classifier heads ----------------
__global__ __launch_bounds__(128) void pool_head(const float* __restrict__ h2,
                                                 const int* __restrict__ batch,
                                                 const float* __restrict__ W_cls,
                                                 const float* __restrict__ b_cls,
                                                 const float* __restrict__ W_conf,
                                                 const float* __restrict__ b_conf,
                                                 float* __restrict__ out) {
    int b = blockIdx.x;
    int t = threadIdx.x;  // 0..127 = channel
    // lower_bound over sorted batch
    int lo = 0, hi = NN;
    while (lo < hi) { int mid = (lo + hi) >> 1; if (batch[mid] < b) lo = mid + 1; else hi = mid; }
    int start = lo;
    lo = 0; hi = NN;
    while (lo < hi) { int mid = (lo + hi) >> 1; if (batch[mid] < b + 1) lo = mid + 1; else hi = mid; }
    int end = lo;

    float acc = 0.f;
    for (int n = start; n < end; ++n) acc += h2[(size_t)n * 128 + t];
    float cnt = (float)(end - start);
    float emb = acc / fmaxf(cnt, 1.f);
    __shared__ float se[128];
    se[t] = emb;
    __syncthreads();
    if (t == 0) {
        float v = b_cls[0];
        for (int c = 0; c < 128; ++c) v += se[c] * W_cls[c * 2 + 0];
        out[b * 2 + 0] = v;
    } else if (t == 1) {
        float v = b_cls[1];
        for (int c = 0; c < 128; ++c) v += se[c] * W_cls[c * 2 + 1];
        out[b * 2 + 1] = v;
    } else if (t == 2) {
        float v = b_conf[0];
        for (int c = 0; c < 128; ++c) v += se[c] * W_conf[c];
        out[128 + b] = 1.f / (1.f + expf(-v));
    }
}

extern "C" void kernel_launch(void* const* d_in, const int* in_sizes, int n_in,
                              void* d_out, int out_size, void* d_ws, size_t ws_size,
                              hipStream_t stream) {
    const float* x        = (const float*)d_in[0];
    const int*   ei       = (const int*)d_in[1];
    const int*   batch    = (const int*)d_in[2];
    const float* W_in     = (const float*)d_in[3];
    const float* b_in     = (const float*)d_in[4];
    const float* W1       = (const float*)d_in[5];
    const float* att_src1 = (const float*)d_in[6];
    const float* att_dst1 = (const float*)d_in[7];
    const float* b1       = (const float*)d_in[8];
    const float* W2       = (const float*)d_in[9];
    const float* att_src2 = (const float*)d_in[10];
    const float* att_dst2 = (const float*)d_in[11];
    const float* b2       = (const float*)d_in[12];
    const float* W_cls    = (const float*)d_in[13];
    const float* b_cls    = (const float*)d_in[14];
    const float* W_conf   = (const float*)d_in[15];
    const float* b_conf   = (const float*)d_in[16];
    float* out = (float*)d_out;

    char* ws = (char*)d_ws;
    float* bufA = (float*)(ws);                       // 51.2MB: h0, then h1
    float* hW1  = (float*)(ws + 51200000);            // 51.2MB: hW1; later hW2 + h2
    float* hW2  = hW1;                                // 25.6MB (after hW1 dead)
    float* h2   = (float*)(ws + 51200000 + 25600000); // 25.6MB
    size_t base = 102400000;
    float* a_s1   = (float*)(ws + base + 0);
    float* a_d1   = (float*)(ws + base + 800000);
    float* a_s2   = (float*)(ws + base + 1600000);
    float* a_d2   = (float*)(ws + base + 2400000);
    int*   deg    = (int*)(ws + base + 3200000);
    int*   rowp   = (int*)(ws + base + 3400000);
    int*   cursor = (int*)(ws + base + 3600064);
    int*   colidx = (int*)(ws + base + 3800064);

    // CSR build
    hipMemsetAsync(deg, 0, NN * sizeof(int), stream);
    k_hist<<<NE / 256, 256, 0, stream>>>(ei, deg);
    k_scan<<<1, 1024, 0, stream>>>(deg, rowp, cursor);
    k_scatter<<<NE / 256, 256, 0, stream>>>(ei, cursor, colidx);

    // h0 = relu(x @ W_in + b_in)
    gemm_f32<1, 1><<<dim3(782, 4), 256, 0, stream>>>(x, W_in, b_in, bufA, NN, IND, HIDD);
    // hW1 = h0 @ W1
    gemm_f32<0, 0><<<dim3(782, 4), 256, 0, stream>>>(bufA, W1, nullptr, hW1, NN, HIDD, HIDD);
    att_dots<256><<<12500, 256, 0, stream>>>(hW1, att_src1, att_dst1, a_s1, a_d1);
    // h1 = relu(agg1 + b1) -> bufA (h0 dead)
    gat_agg<256><<<12500, 256, 0, stream>>>(hW1, a_s1, a_d1, rowp, colidx, b1, bufA);
    // hW2 = h1 @ W2 (hW1 dead)
    gemm_f32<0, 0><<<dim3(782, 2), 256, 0, stream>>>(bufA, W2, nullptr, hW2, NN, HIDD, 128);
    att_dots<128><<<12500, 256, 0, stream>>>(hW2, att_src2, att_dst2, a_s2, a_d2);
    // h2 = relu(agg2 + b2)
    gat_agg<128><<<12500, 256, 0, stream>>>(hW2, a_s2, a_d2, rowp, colidx, b2, h2);
    // pool + heads
    pool_head<<<NB, 128, 0, stream>>>(h2, batch, W_cls, b_cls, W_conf, b_conf, out);
}

// Round 2
// 963.838 us; speedup vs baseline: 1.8133x; 1.8133x over previous
//
#include <hip/hip_runtime.h>
#include <math.h>

#define NN 50000
#define NE 800000
#define NB 64
#define IND 773

typedef __attribute__((ext_vector_type(8))) short short8_t;
typedef __attribute__((ext_vector_type(4))) float f32x4;

__device__ __forceinline__ float lrelu(float x) { return x > 0.f ? x : 0.2f * x; }
__device__ __forceinline__ short f2b(float f) {
    unsigned u = __float_as_uint(f);
    unsigned r = (u + 0x7fffu + ((u >> 16) & 1u)) >> 16;  // RNE
    return (short)r;
}
__device__ __forceinline__ float b2f(short s) {
    return __uint_as_float(((unsigned)(unsigned short)s) << 16);
}

// ---------------- bf16 MFMA GEMM: C(bf16) = act(A @ Bt^T (+ bias)) ----------------
// A: [M][K] fp32 (AFP32=1) or bf16; Bt: [N][Kb] bf16 (pre-transposed, K padded to Kb).
// 128x128 tile, 256 threads = 4 waves (2x2), each wave 64x64 = 4x4 frags of 16x16x32.
template<int RELU, int HASB, int AFP32>
__global__ __launch_bounds__(256) void gemm_mfma(const void* __restrict__ Ap,
                                                 const short* __restrict__ Bt,
                                                 const float* __restrict__ bias,
                                                 short* __restrict__ C,
                                                 int M, int K, int Kb, int N) {
    __shared__ short As[128 * 40];  // row-padded 32->40 elems (80B): ~2-way banks
    __shared__ short Bs[128 * 40];
    const int t = threadIdx.x;
    const int w = t >> 6, l = t & 63;
    const int l15 = l & 15, lh = l >> 4;
    const int bm = blockIdx.x * 128, bn = blockIdx.y * 128;
    const int wr = (w >> 1) * 64, wc = (w & 1) * 64;
    const int srow = t >> 1;         // staging row 0..127
    const int scb = (t & 1) << 4;    // staging col base 0 or 16

    f32x4 acc[4][4];
#pragma unroll
    for (int i = 0; i < 4; ++i)
#pragma unroll
        for (int j = 0; j < 4; ++j) acc[i][j] = (f32x4){0.f, 0.f, 0.f, 0.f};

    for (int k0 = 0; k0 < K; k0 += 32) {
        __syncthreads();
        // ---- stage A tile [128][32] ----
        {
            int gm = bm + srow;
            short o[16];
            if (AFP32) {
                const float* A32 = (const float*)Ap;
                const float* ap = A32 + (size_t)gm * K + k0 + scb;
#pragma unroll
                for (int j = 0; j < 16; ++j) {
                    int gk = k0 + scb + j;
                    o[j] = (gm < M && gk < K) ? f2b(ap[j]) : (short)0;
                }
            } else {
                const short* A16 = (const short*)Ap;
                if (gm < M) {
                    const short* ap = A16 + (size_t)gm * K + k0 + scb;
                    *(short8_t*)&o[0] = *(const short8_t*)(ap);
                    *(short8_t*)&o[8] = *(const short8_t*)(ap + 8);
                } else {
#pragma unroll
                    for (int j = 0; j < 16; ++j) o[j] = 0;
                }
            }
            *(short8_t*)&As[srow * 40 + scb] = *(short8_t*)&o[0];
            *(short8_t*)&As[srow * 40 + scb + 8] = *(short8_t*)&o[8];
        }
        // ---- stage B tile: Bt rows = output cols ----
        {
            const short* bp = Bt + (size_t)(bn + srow) * Kb + k0 + scb;
            short8_t b0 = *(const short8_t*)(bp);
            short8_t b1 = *(const short8_t*)(bp + 8);
            *(short8_t*)&Bs[srow * 40 + scb] = b0;
            *(short8_t*)&Bs[srow * 40 + scb + 8] = b1;
        }
        __syncthreads();
        // ---- fragments + MFMA ----
        short8_t af[4], bfr[4];
#pragma unroll
        for (int mi = 0; mi < 4; ++mi)
            af[mi] = *(const short8_t*)&As[(wr + mi * 16 + l15) * 40 + lh * 8];
#pragma unroll
        for (int ni = 0; ni < 4; ++ni)
            bfr[ni] = *(const short8_t*)&Bs[(wc + ni * 16 + l15) * 40 + lh * 8];
#pragma unroll
        for (int mi = 0; mi < 4; ++mi)
#pragma unroll
            for (int ni = 0; ni < 4; ++ni)
                acc[mi][ni] = __builtin_amdgcn_mfma_f32_16x16x32_bf16(af[mi], bfr[ni], acc[mi][ni], 0, 0, 0);
    }

    // ---- epilogue: C/D layout col=lane&15, row=(lane>>4)*4+r ----
#pragma unroll
    for (int mi = 0; mi < 4; ++mi) {
#pragma unroll
        for (int r = 0; r < 4; ++r) {
            int grow = bm + wr + mi * 16 + lh * 4 + r;
            if (grow >= M) continue;
#pragma unroll
            for (int ni = 0; ni < 4; ++ni) {
                int gcol = bn + wc + ni * 16 + l15;
                float v = acc[mi][ni][r];
                if (HASB) v += bias[gcol];
                if (RELU) v = fmaxf(v, 0.f);
                C[(size_t)grow * N + gcol] = f2b(v);
            }
        }
    }
}

// ---------------- weight transpose+pad cast: Wt[n][k] = bf16(W[k][n]) ----------------
__global__ void k_wt(const float* __restrict__ W, short* __restrict__ Wt,
                     int K, int N, int Kp) {
    int idx = blockIdx.x * 256 + threadIdx.x;
    if (idx >= N * Kp) return;
    int n = idx / Kp, k = idx - n * Kp;
    Wt[idx] = (k < K) ? f2b(W[(size_t)k * N + n]) : (short)0;
}

// ---------------- attention dot products ----------------
template<int HD>
__global__ __launch_bounds__(256) void att_dots(const short* __restrict__ hW,
                                                const float* __restrict__ att_s,
                                                const float* __restrict__ att_d,
                                                float* __restrict__ a_s,
                                                float* __restrict__ a_d) {
    const int CPL = HD / 64;
    int node = blockIdx.x * 4 + (threadIdx.x >> 6);
    int lane = threadIdx.x & 63;
    if (node >= NN) return;
    const short* row = hW + (size_t)node * HD + lane * CPL;
    float s = 0.f, d = 0.f;
#pragma unroll
    for (int j = 0; j < CPL; ++j) {
        float v = b2f(row[j]);
        s += v * att_s[lane * CPL + j];
        d += v * att_d[lane * CPL + j];
    }
#pragma unroll
    for (int off = 1; off < 16; off <<= 1) {
        s += __shfl_xor(s, off);
        d += __shfl_xor(d, off);
    }
    int h = lane >> 4;
    if ((lane & 15) == 0) {
        a_s[node * 4 + h] = s;
        a_d[node * 4 + h] = d;
    }
}

// ---------------- CSR build ----------------
__global__ void k_hist(const int* __restrict__ ei, int* __restrict__ deg) {
    int e = blockIdx.x * 256 + threadIdx.x;
    if (e >= NE) return;
    atomicAdd(&deg[ei[NE + e]], 1);
}

__global__ __launch_bounds__(1024) void k_scan(const int* __restrict__ deg,
                                               int* __restrict__ row_ptr,
                                               int* __restrict__ cursor) {
    const int CH = (NN + 1023) / 1024;
    int t = threadIdx.x;
    int lo = t * CH, hi = lo + CH;
    if (hi > NN) hi = NN;
    int s = 0;
    for (int i = lo; i < hi; ++i) s += deg[i];
    __shared__ int sums[1024];
    sums[t] = s;
    __syncthreads();
    for (int off = 1; off < 1024; off <<= 1) {
        int v = (t >= off) ? sums[t - off] : 0;
        __syncthreads();
        sums[t] += v;
        __syncthreads();
    }
    int run = (t == 0) ? 0 : sums[t - 1];
    for (int i = lo; i < hi; ++i) {
        row_ptr[i] = run;
        cursor[i] = run;
        run += deg[i];
    }
    if (t == 1023) row_ptr[NN] = NE;
}

__global__ void k_scatter(const int* __restrict__ ei, int* __restrict__ cursor,
                          int* __restrict__ colidx) {
    int e = blockIdx.x * 256 + threadIdx.x;
    if (e >= NE) return;
    int s = ei[e], d = ei[NE + e];
    int pos = atomicAdd(&cursor[d], 1);
    colidx[pos] = s;
}

// ---------------- fused GAT aggregation (one wave per dst node), bf16 in/out ----------------
template<int HD>
__global__ __launch_bounds__(256) void gat_agg(const short* __restrict__ hW,
                                               const float* __restrict__ a_s,
                                               const float* __restrict__ a_d,
                                               const int* __restrict__ row_ptr,
                                               const int* __restrict__ colidx,
                                               const float* __restrict__ bias,
                                               short* __restrict__ outp) {
    const int CPL = HD / 64;
    int node = blockIdx.x * 4 + (threadIdx.x >> 6);
    int lane = threadIdx.x & 63;
    if (node >= NN) return;
    int h = lane >> 4;
    int start = row_ptr[node], end = row_ptr[node + 1];
    float adst = a_d[node * 4 + h];
    float aself = a_s[node * 4 + h];

    float m = lrelu(aself + adst);
    for (int e = start; e < end; ++e) {
        int s = colidx[e];
        m = fmaxf(m, lrelu(a_s[s * 4 + h] + adst));
    }

    float acc[CPL];
    float z;
    {
        float ex = __expf(lrelu(aself + adst) - m);
        z = ex;
        const short* row = hW + (size_t)node * HD + lane * CPL;
        float v[CPL];
        if (CPL == 4) { short4 q = *(const short4*)row; v[0]=b2f(q.x); v[1]=b2f(q.y); v[2]=b2f(q.z); v[3]=b2f(q.w); }
        else          { short2 q = *(const short2*)row; v[0]=b2f(q.x); v[1]=b2f(q.y); }
#pragma unroll
        for (int j = 0; j < CPL; ++j) acc[j] = ex * v[j];
    }
    for (int e = start; e < end; ++e) {
        int s = colidx[e];
        float ex = __expf(lrelu(a_s[s * 4 + h] + adst) - m);
        z += ex;
        const short* row = hW + (size_t)s * HD + lane * CPL;
        float v[CPL];
        if (CPL == 4) { short4 q = *(const short4*)row; v[0]=b2f(q.x); v[1]=b2f(q.y); v[2]=b2f(q.z); v[3]=b2f(q.w); }
        else          { short2 q = *(const short2*)row; v[0]=b2f(q.x); v[1]=b2f(q.y); }
#pragma unroll
        for (int j = 0; j < CPL; ++j) acc[j] += ex * v[j];
    }
    float inv = 1.f / (z + 1e-16f);
    short* orow = outp + (size_t)node * HD + lane * CPL;
#pragma unroll
    for (int j = 0; j < CPL; ++j)
        orow[j] = f2b(fmaxf(acc[j] * inv + bias[lane * CPL + j], 0.f));
}

// ---------------- pooling + classifier heads ----------------
__global__ __launch_bounds__(512) void pool_head(const short* __restrict__ h2,
                                                 const int* __restrict__ batch,
                                                 const float* __restrict__ W_cls,
                                                 const float* __restrict__ b_cls,
                                                 const float* __restrict__ W_conf,
                                                 const float* __restrict__ b_conf,
                                                 float* __restrict__ out) {
    int b = blockIdx.x;
    int t = threadIdx.x & 127;  // channel
    int g = threadIdx.x >> 7;   // group 0..3
    int lo = 0, hi = NN;
    while (lo < hi) { int mid = (lo + hi) >> 1; if (batch[mid] < b) lo = mid + 1; else hi = mid; }
    int start = lo;
    lo = 0; hi = NN;
    while (lo < hi) { int mid = (lo + hi) >> 1; if (batch[mid] < b + 1) lo = mid + 1; else hi = mid; }
    int end = lo;

    float acc = 0.f;
    for (int n = start + g; n < end; n += 4) acc += b2f(h2[(size_t)n * 128 + t]);
    __shared__ float se[4][128];
    se[g][t] = acc;
    __syncthreads();
    if (g == 0) {
        float emb = (se[0][t] + se[1][t] + se[2][t] + se[3][t]) /
                    fmaxf((float)(end - start), 1.f);
        se[0][t] = emb;
    }
    __syncthreads();
    if (threadIdx.x == 0) {
        float v = b_cls[0];
        for (int c = 0; c < 128; ++c) v += se[0][c] * W_cls[c * 2 + 0];
        out[b * 2 + 0] = v;
    } else if (threadIdx.x == 1) {
        float v = b_cls[1];
        for (int c = 0; c < 128; ++c) v += se[0][c] * W_cls[c * 2 + 1];
        out[b * 2 + 1] = v;
    } else if (threadIdx.x == 2) {
        float v = b_conf[0];
        for (int c = 0; c < 128; ++c) v += se[0][c] * W_conf[c];
        out[128 + b] = 1.f / (1.f + expf(-v));
    }
}

extern "C" void kernel_launch(void* const* d_in, const int* in_sizes, int n_in,
                              void* d_out, int out_size, void* d_ws, size_t ws_size,
                              hipStream_t stream) {
    const float* x        = (const float*)d_in[0];
    const int*   ei       = (const int*)d_in[1];
    const int*   batch    = (const int*)d_in[2];
    const float* W_in     = (const float*)d_in[3];
    const float* b_in     = (const float*)d_in[4];
    const float* W1       = (const float*)d_in[5];
    const float* att_src1 = (const float*)d_in[6];
    const float* att_dst1 = (const float*)d_in[7];
    const float* b1       = (const float*)d_in[8];
    const float* W2       = (const float*)d_in[9];
    const float* att_src2 = (const float*)d_in[10];
    const float* att_dst2 = (const float*)d_in[11];
    const float* b2       = (const float*)d_in[12];
    const float* W_cls    = (const float*)d_in[13];
    const float* b_cls    = (const float*)d_in[14];
    const float* W_conf   = (const float*)d_in[15];
    const float* b_conf   = (const float*)d_in[16];
    float* out = (float*)d_out;

    char* ws = (char*)d_ws;
    // activations (bf16)
    short* h0  = (short*)(ws + 0);           // [50000][256] 25.6MB
    short* hW1 = (short*)(ws + 25600000);    // [50000][256] 25.6MB
    short* h1  = (short*)(ws + 51200000);    // [50000][256] 25.6MB
    short* hW2 = (short*)(ws + 0);           // [50000][128] 12.8MB (h0 dead)
    short* h2  = (short*)(ws + 12800000);    // [50000][128] 12.8MB
    size_t base = 76800000;
    short* Wt_in = (short*)(ws + base);                 // [256][800]
    short* Wt1   = (short*)(ws + base + 409600);        // [256][256]
    short* Wt2   = (short*)(ws + base + 540672);        // [128][256]
    float* a_s1  = (float*)(ws + base + 606208);
    float* a_d1  = (float*)(ws + base + 1406208);
    float* a_s2  = (float*)(ws + base + 2206208);
    float* a_d2  = (float*)(ws + base + 3006208);
    int*   deg    = (int*)(ws + base + 3806208);
    int*   rowp   = (int*)(ws + base + 4006208);
    int*   cursor = (int*)(ws + base + 4206272);
    int*   colidx = (int*)(ws + base + 4406272);

    // weight casts (transpose + K-pad)
    k_wt<<<(256 * 800 + 255) / 256, 256, 0, stream>>>(W_in, Wt_in, IND, 256, 800);
    k_wt<<<(256 * 256 + 255) / 256, 256, 0, stream>>>(W1, Wt1, 256, 256, 256);
    k_wt<<<(128 * 256 + 255) / 256, 256, 0, stream>>>(W2, Wt2, 256, 128, 256);

    // CSR build
    hipMemsetAsync(deg, 0, NN * sizeof(int), stream);
    k_hist<<<NE / 256, 256, 0, stream>>>(ei, deg);
    k_scan<<<1, 1024, 0, stream>>>(deg, rowp, cursor);
    k_scatter<<<NE / 256, 256, 0, stream>>>(ei, cursor, colidx);

    // h0 = relu(x @ W_in + b_in)  (fp32 A, converted in staging)
    gemm_mfma<1, 1, 1><<<dim3(391, 2), 256, 0, stream>>>(x, Wt_in, b_in, h0, NN, IND, 800, 256);
    // hW1 = h0 @ W1
    gemm_mfma<0, 0, 0><<<dim3(391, 2), 256, 0, stream>>>(h0, Wt1, nullptr, hW1, NN, 256, 256, 256);
    att_dots<256><<<12500, 256, 0, stream>>>(hW1, att_src1, att_dst1, a_s1, a_d1);
    gat_agg<256><<<12500, 256, 0, stream>>>(hW1, a_s1, a_d1, rowp, colidx, b1, h1);
    // hW2 = h1 @ W2
    gemm_mfma<0, 0, 0><<<dim3(391, 1), 256, 0, stream>>>(h1, Wt2, nullptr, hW2, NN, 256, 256, 128);
    att_dots<128><<<12500, 256, 0, stream>>>(hW2, att_src2, att_dst2, a_s2, a_d2);
    gat_agg<128><<<12500, 256, 0, stream>>>(hW2, a_s2, a_d2, rowp, colidx, b2, h2);
    pool_head<<<NB, 512, 0, stream>>>(h2, batch, W_cls, b_cls, W_conf, b_conf, out);
}

// Round 3
// 544.329 us; speedup vs baseline: 3.2108x; 1.7707x over previous
//
#include <hip/hip_runtime.h>
#include <math.h>

#define NN 50000
#define NE 800000
#define NB 64
#define IND 773

typedef __attribute__((ext_vector_type(8))) short short8_t;
typedef __attribute__((ext_vector_type(4))) float f32x4;

__device__ __forceinline__ float lrelu(float x) { return x > 0.f ? x : 0.2f * x; }
__device__ __forceinline__ short f2b(float f) {
    unsigned u = __float_as_uint(f);
    unsigned r = (u + 0x7fffu + ((u >> 16) & 1u)) >> 16;  // RNE
    return (short)r;
}
__device__ __forceinline__ float b2f(short s) {
    return __uint_as_float(((unsigned)(unsigned short)s) << 16);
}

// ---------------- bf16 MFMA GEMM: C(bf16) = act(A @ Bt^T (+ bias)) ----------------
// A: [M][K] fp32 (AFP32=1, converted in coalesced staging) or bf16.
// Bt: [N][Kb] bf16 (pre-transposed, K zero-padded to Kb).
// 128x128 tile, 256 threads = 4 waves (2x2), each wave 64x64 = 4x4 frags of 16x16x32.
template<int RELU, int HASB, int AFP32>
__global__ __launch_bounds__(256) void gemm_mfma(const void* __restrict__ Ap,
                                                 const short* __restrict__ Bt,
                                                 const float* __restrict__ bias,
                                                 short* __restrict__ C,
                                                 int M, int K, int Kb, int N) {
    __shared__ short As[128 * 40];  // row-padded 32->40 elems (80B)
    __shared__ short Bs[128 * 40];
    const int t = threadIdx.x;
    const int w = t >> 6, l = t & 63;
    const int l15 = l & 15, lh = l >> 4;
    const int bm = blockIdx.x * 128, bn = blockIdx.y * 128;
    const int wr = (w >> 1) * 64, wc = (w & 1) * 64;
    const int srow = t >> 1;         // bf16 staging row 0..127
    const int scb = (t & 1) << 4;    // bf16 staging col base 0 or 16

    f32x4 acc[4][4];
#pragma unroll
    for (int i = 0; i < 4; ++i)
#pragma unroll
        for (int j = 0; j < 4; ++j) acc[i][j] = (f32x4){0.f, 0.f, 0.f, 0.f};

    for (int k0 = 0; k0 < K; k0 += 32) {
        __syncthreads();
        // ---- stage A tile [128][32] ----
        if (AFP32) {
            const float* A32 = (const float*)Ap;
            // 4 float4 loads/thread, 8 consecutive lanes cover 128B of one row.
#pragma unroll
            for (int i = 0; i < 4; ++i) {
                int fid = i * 256 + t;
                int row = fid >> 3;
                int cb = (fid & 7) * 4;
                int gm = bm + row, gk = k0 + cb;
                float4 v = make_float4(0.f, 0.f, 0.f, 0.f);
                if (gm < M) {
                    const float* ap = A32 + (size_t)gm * K;
                    if (gk + 3 < K) v = *(const float4*)(ap + gk);
                    else {
                        if (gk + 0 < K) v.x = ap[gk + 0];
                        if (gk + 1 < K) v.y = ap[gk + 1];
                        if (gk + 2 < K) v.z = ap[gk + 2];
                        if (gk + 3 < K) v.w = ap[gk + 3];
                    }
                }
                short4 o; o.x = f2b(v.x); o.y = f2b(v.y); o.z = f2b(v.z); o.w = f2b(v.w);
                *(short4*)&As[row * 40 + cb] = o;
            }
        } else {
            const short* A16 = (const short*)Ap;
            int gm = bm + srow;
            short o[16];
            if (gm < M) {
                const short* ap = A16 + (size_t)gm * K + k0 + scb;
                *(short8_t*)&o[0] = *(const short8_t*)(ap);
                *(short8_t*)&o[8] = *(const short8_t*)(ap + 8);
            } else {
#pragma unroll
                for (int j = 0; j < 16; ++j) o[j] = 0;
            }
            *(short8_t*)&As[srow * 40 + scb] = *(short8_t*)&o[0];
            *(short8_t*)&As[srow * 40 + scb + 8] = *(short8_t*)&o[8];
        }
        // ---- stage B tile: Bt rows = output cols ----
        {
            const short* bp = Bt + (size_t)(bn + srow) * Kb + k0 + scb;
            short8_t b0 = *(const short8_t*)(bp);
            short8_t b1 = *(const short8_t*)(bp + 8);
            *(short8_t*)&Bs[srow * 40 + scb] = b0;
            *(short8_t*)&Bs[srow * 40 + scb + 8] = b1;
        }
        __syncthreads();
        // ---- fragments + MFMA ----
        short8_t af[4], bfr[4];
#pragma unroll
        for (int mi = 0; mi < 4; ++mi)
            af[mi] = *(const short8_t*)&As[(wr + mi * 16 + l15) * 40 + lh * 8];
#pragma unroll
        for (int ni = 0; ni < 4; ++ni)
            bfr[ni] = *(const short8_t*)&Bs[(wc + ni * 16 + l15) * 40 + lh * 8];
#pragma unroll
        for (int mi = 0; mi < 4; ++mi)
#pragma unroll
            for (int ni = 0; ni < 4; ++ni)
                acc[mi][ni] = __builtin_amdgcn_mfma_f32_16x16x32_bf16(af[mi], bfr[ni], acc[mi][ni], 0, 0, 0);
    }

    // ---- epilogue: C/D layout col=lane&15, row=(lane>>4)*4+r ----
#pragma unroll
    for (int mi = 0; mi < 4; ++mi) {
#pragma unroll
        for (int r = 0; r < 4; ++r) {
            int grow = bm + wr + mi * 16 + lh * 4 + r;
            if (grow >= M) continue;
#pragma unroll
            for (int ni = 0; ni < 4; ++ni) {
                int gcol = bn + wc + ni * 16 + l15;
                float v = acc[mi][ni][r];
                if (HASB) v += bias[gcol];
                if (RELU) v = fmaxf(v, 0.f);
                C[(size_t)grow * N + gcol] = f2b(v);
            }
        }
    }
}

// ---------------- weight transpose+pad cast: Wt[n][k] = bf16(W[k][n]) ----------------
__global__ void k_wt(const float* __restrict__ W, short* __restrict__ Wt,
                     int K, int N, int Kp) {
    int idx = blockIdx.x * 256 + threadIdx.x;
    if (idx >= N * Kp) return;
    int n = idx / Kp, k = idx - n * Kp;
    Wt[idx] = (k < K) ? f2b(W[(size_t)k * N + n]) : (short)0;
}

// ---------------- attention dot products ----------------
template<int HD>
__global__ __launch_bounds__(256) void att_dots(const short* __restrict__ hW,
                                                const float* __restrict__ att_s,
                                                const float* __restrict__ att_d,
                                                float* __restrict__ a_s,
                                                float* __restrict__ a_d) {
    const int CPL = HD / 64;
    int node = blockIdx.x * 4 + (threadIdx.x >> 6);
    int lane = threadIdx.x & 63;
    if (node >= NN) return;
    const short* row = hW + (size_t)node * HD + lane * CPL;
    float s = 0.f, d = 0.f;
#pragma unroll
    for (int j = 0; j < CPL; ++j) {
        float v = b2f(row[j]);
        s += v * att_s[lane * CPL + j];
        d += v * att_d[lane * CPL + j];
    }
#pragma unroll
    for (int off = 1; off < 16; off <<= 1) {
        s += __shfl_xor(s, off);
        d += __shfl_xor(d, off);
    }
    int h = lane >> 4;
    if ((lane & 15) == 0) {
        a_s[node * 4 + h] = s;
        a_d[node * 4 + h] = d;
    }
}

// ---------------- CSR build ----------------
__global__ void k_hist(const int* __restrict__ ei, int* __restrict__ deg) {
    int e = blockIdx.x * 256 + threadIdx.x;
    if (e >= NE) return;
    atomicAdd(&deg[ei[NE + e]], 1);
}

__global__ __launch_bounds__(1024) void k_scan(const int* __restrict__ deg,
                                               int* __restrict__ row_ptr,
                                               int* __restrict__ cursor) {
    const int CH = (NN + 1023) / 1024;
    int t = threadIdx.x;
    int lo = t * CH, hi = lo + CH;
    if (hi > NN) hi = NN;
    int s = 0;
    for (int i = lo; i < hi; ++i) s += deg[i];
    __shared__ int sums[1024];
    sums[t] = s;
    __syncthreads();
    for (int off = 1; off < 1024; off <<= 1) {
        int v = (t >= off) ? sums[t - off] : 0;
        __syncthreads();
        sums[t] += v;
        __syncthreads();
    }
    int run = (t == 0) ? 0 : sums[t - 1];
    for (int i = lo; i < hi; ++i) {
        row_ptr[i] = run;
        cursor[i] = run;
        run += deg[i];
    }
    if (t == 1023) row_ptr[NN] = NE;
}

__global__ void k_scatter(const int* __restrict__ ei, int* __restrict__ cursor,
                          int* __restrict__ colidx) {
    int e = blockIdx.x * 256 + threadIdx.x;
    if (e >= NE) return;
    int s = ei[e], d = ei[NE + e];
    int pos = atomicAdd(&cursor[d], 1);
    colidx[pos] = s;
}

// ---------------- fused GAT aggregation (one wave per dst node), bf16 in/out ----------------
// Single pass: softmax shifted by the self-loop score (exact; logits are ~0.03 scale).
// Edge loop unrolled x4 for memory-level parallelism on the row gathers.
template<int HD>
__global__ __launch_bounds__(256) void gat_agg(const short* __restrict__ hW,
                                               const float* __restrict__ a_s,
                                               const float* __restrict__ a_d,
                                               const int* __restrict__ row_ptr,
                                               const int* __restrict__ colidx,
                                               const float* __restrict__ bias,
                                               short* __restrict__ outp) {
    const int CPL = HD / 64;
    int node = blockIdx.x * 4 + (threadIdx.x >> 6);
    int lane = threadIdx.x & 63;
    if (node >= NN) return;
    int h = lane >> 4;
    int start = row_ptr[node], end = row_ptr[node + 1];
    float adst = a_d[node * 4 + h];
    float eself = lrelu(a_s[node * 4 + h] + adst);

    float z = 1.f;  // exp(eself - eself)
    float acc[CPL];
    {
        const short* row = hW + (size_t)node * HD + lane * CPL;
        if (CPL == 4) { short4 q = *(const short4*)row; acc[0]=b2f(q.x); acc[1]=b2f(q.y); acc[2]=b2f(q.z); acc[3]=b2f(q.w); }
        else          { short2 q = *(const short2*)row; acc[0]=b2f(q.x); acc[1]=b2f(q.y); }
    }
    int e = start;
    for (; e + 4 <= end; e += 4) {
        int s0 = colidx[e], s1 = colidx[e + 1], s2 = colidx[e + 2], s3 = colidx[e + 3];
        float x0 = a_s[s0 * 4 + h], x1 = a_s[s1 * 4 + h];
        float x2 = a_s[s2 * 4 + h], x3 = a_s[s3 * 4 + h];
        const short* r0 = hW + (size_t)s0 * HD + lane * CPL;
        const short* r1 = hW + (size_t)s1 * HD + lane * CPL;
        const short* r2 = hW + (size_t)s2 * HD + lane * CPL;
        const short* r3 = hW + (size_t)s3 * HD + lane * CPL;
        float v0[CPL], v1[CPL], v2[CPL], v3[CPL];
        if (CPL == 4) {
            short4 q0 = *(const short4*)r0, q1 = *(const short4*)r1;
            short4 q2 = *(const short4*)r2, q3 = *(const short4*)r3;
            v0[0]=b2f(q0.x); v0[1]=b2f(q0.y); v0[2]=b2f(q0.z); v0[3]=b2f(q0.w);
            v1[0]=b2f(q1.x); v1[1]=b2f(q1.y); v1[2]=b2f(q1.z); v1[3]=b2f(q1.w);
            v2[0]=b2f(q2.x); v2[1]=b2f(q2.y); v2[2]=b2f(q2.z); v2[3]=b2f(q2.w);
            v3[0]=b2f(q3.x); v3[1]=b2f(q3.y); v3[2]=b2f(q3.z); v3[3]=b2f(q3.w);
        } else {
            short2 q0 = *(const short2*)r0, q1 = *(const short2*)r1;
            short2 q2 = *(const short2*)r2, q3 = *(const short2*)r3;
            v0[0]=b2f(q0.x); v0[1]=b2f(q0.y);
            v1[0]=b2f(q1.x); v1[1]=b2f(q1.y);
            v2[0]=b2f(q2.x); v2[1]=b2f(q2.y);
            v3[0]=b2f(q3.x); v3[1]=b2f(q3.y);
        }
        float e0 = __expf(lrelu(x0 + adst) - eself);
        float e1 = __expf(lrelu(x1 + adst) - eself);
        float e2 = __expf(lrelu(x2 + adst) - eself);
        float e3 = __expf(lrelu(x3 + adst) - eself);
        z += (e0 + e1) + (e2 + e3);
#pragma unroll
        for (int j = 0; j < CPL; ++j)
            acc[j] += e0 * v0[j] + e1 * v1[j] + e2 * v2[j] + e3 * v3[j];
    }
    for (; e < end; ++e) {
        int s = colidx[e];
        float ex = __expf(lrelu(a_s[s * 4 + h] + adst) - eself);
        z += ex;
        const short* row = hW + (size_t)s * HD + lane * CPL;
        float v[CPL];
        if (CPL == 4) { short4 q = *(const short4*)row; v[0]=b2f(q.x); v[1]=b2f(q.y); v[2]=b2f(q.z); v[3]=b2f(q.w); }
        else          { short2 q = *(const short2*)row; v[0]=b2f(q.x); v[1]=b2f(q.y); }
#pragma unroll
        for (int j = 0; j < CPL; ++j) acc[j] += ex * v[j];
    }
    float inv = 1.f / z;
    short* orow = outp + (size_t)node * HD + lane * CPL;
#pragma unroll
    for (int j = 0; j < CPL; ++j)
        orow[j] = f2b(fmaxf(acc[j] * inv + bias[lane * CPL + j], 0.f));
}

// ---------------- pooling + classifier heads ----------------
__global__ __launch_bounds__(512) void pool_head(const short* __restrict__ h2,
                                                 const int* __restrict__ batch,
                                                 const float* __restrict__ W_cls,
                                                 const float* __restrict__ b_cls,
                                                 const float* __restrict__ W_conf,
                                                 const float* __restrict__ b_conf,
                                                 float* __restrict__ out) {
    int b = blockIdx.x;
    int t = threadIdx.x & 127;  // channel
    int g = threadIdx.x >> 7;   // group 0..3
    int lo = 0, hi = NN;
    while (lo < hi) { int mid = (lo + hi) >> 1; if (batch[mid] < b) lo = mid + 1; else hi = mid; }
    int start = lo;
    lo = 0; hi = NN;
    while (lo < hi) { int mid = (lo + hi) >> 1; if (batch[mid] < b + 1) lo = mid + 1; else hi = mid; }
    int end = lo;

    float acc = 0.f;
    for (int n = start + g; n < end; n += 4) acc += b2f(h2[(size_t)n * 128 + t]);
    __shared__ float se[4][128];
    se[g][t] = acc;
    __syncthreads();
    if (g == 0) {
        float emb = (se[0][t] + se[1][t] + se[2][t] + se[3][t]) /
                    fmaxf((float)(end - start), 1.f);
        se[0][t] = emb;
    }
    __syncthreads();
    if (threadIdx.x == 0) {
        float v = b_cls[0];
        for (int c = 0; c < 128; ++c) v += se[0][c] * W_cls[c * 2 + 0];
        out[b * 2 + 0] = v;
    } else if (threadIdx.x == 1) {
        float v = b_cls[1];
        for (int c = 0; c < 128; ++c) v += se[0][c] * W_cls[c * 2 + 1];
        out[b * 2 + 1] = v;
    } else if (threadIdx.x == 2) {
        float v = b_conf[0];
        for (int c = 0; c < 128; ++c) v += se[0][c] * W_conf[c];
        out[128 + b] = 1.f / (1.f + expf(-v));
    }
}

extern "C" void kernel_launch(void* const* d_in, const int* in_sizes, int n_in,
                              void* d_out, int out_size, void* d_ws, size_t ws_size,
                              hipStream_t stream) {
    const float* x        = (const float*)d_in[0];
    const int*   ei       = (const int*)d_in[1];
    const int*   batch    = (const int*)d_in[2];
    const float* W_in     = (const float*)d_in[3];
    const float* b_in     = (const float*)d_in[4];
    const float* W1       = (const float*)d_in[5];
    const float* att_src1 = (const float*)d_in[6];
    const float* att_dst1 = (const float*)d_in[7];
    const float* b1       = (const float*)d_in[8];
    const float* W2       = (const float*)d_in[9];
    const float* att_src2 = (const float*)d_in[10];
    const float* att_dst2 = (const float*)d_in[11];
    const float* b2       = (const float*)d_in[12];
    const float* W_cls    = (const float*)d_in[13];
    const float* b_cls    = (const float*)d_in[14];
    const float* W_conf   = (const float*)d_in[15];
    const float* b_conf   = (const float*)d_in[16];
    float* out = (float*)d_out;

    char* ws = (char*)d_ws;
    // activations (bf16)
    short* h0  = (short*)(ws + 0);           // [50000][256] 25.6MB
    short* hW1 = (short*)(ws + 25600000);    // [50000][256] 25.6MB
    short* h1  = (short*)(ws + 51200000);    // [50000][256] 25.6MB
    short* hW2 = (short*)(ws + 0);           // [50000][128] 12.8MB (h0 dead)
    short* h2  = (short*)(ws + 12800000);    // [50000][128] 12.8MB
    size_t base = 76800000;
    short* Wt_in = (short*)(ws + base);                 // [256][800]
    short* Wt1   = (short*)(ws + base + 409600);        // [256][256]
    short* Wt2   = (short*)(ws + base + 540672);        // [128][256]
    float* a_s1  = (float*)(ws + base + 606208);
    float* a_d1  = (float*)(ws + base + 1406208);
    float* a_s2  = (float*)(ws + base + 2206208);
    float* a_d2  = (float*)(ws + base + 3006208);
    int*   deg    = (int*)(ws + base + 3806208);
    int*   rowp   = (int*)(ws + base + 4006208);
    int*   cursor = (int*)(ws + base + 4206272);
    int*   colidx = (int*)(ws + base + 4406272);

    // weight casts (transpose + K-pad)
    k_wt<<<(256 * 800 + 255) / 256, 256, 0, stream>>>(W_in, Wt_in, IND, 256, 800);
    k_wt<<<(256 * 256 + 255) / 256, 256, 0, stream>>>(W1, Wt1, 256, 256, 256);
    k_wt<<<(128 * 256 + 255) / 256, 256, 0, stream>>>(W2, Wt2, 256, 128, 256);

    // CSR build
    hipMemsetAsync(deg, 0, NN * sizeof(int), stream);
    k_hist<<<NE / 256, 256, 0, stream>>>(ei, deg);
    k_scan<<<1, 1024, 0, stream>>>(deg, rowp, cursor);
    k_scatter<<<NE / 256, 256, 0, stream>>>(ei, cursor, colidx);

    // h0 = relu(x @ W_in + b_in)  (fp32 A, converted in staging)
    gemm_mfma<1, 1, 1><<<dim3(391, 2), 256, 0, stream>>>(x, Wt_in, b_in, h0, NN, IND, 800, 256);
    // hW1 = h0 @ W1
    gemm_mfma<0, 0, 0><<<dim3(391, 2), 256, 0, stream>>>(h0, Wt1, nullptr, hW1, NN, 256, 256, 256);
    att_dots<256><<<12500, 256, 0, stream>>>(hW1, att_src1, att_dst1, a_s1, a_d1);
    gat_agg<256><<<12500, 256, 0, stream>>>(hW1, a_s1, a_d1, rowp, colidx, b1, h1);
    // hW2 = h1 @ W2
    gemm_mfma<0, 0, 0><<<dim3(391, 1), 256, 0, stream>>>(h1, Wt2, nullptr, hW2, NN, 256, 256, 128);
    att_dots<128><<<12500, 256, 0, stream>>>(hW2, att_src2, att_dst2, a_s2, a_d2);
    gat_agg<128><<<12500, 256, 0, stream>>>(hW2, a_s2, a_d2, rowp, colidx, b2, h2);
    pool_head<<<NB, 512, 0, stream>>>(h2, batch, W_cls, b_cls, W_conf, b_conf, out);
}